// Round 5
// baseline (457.022 us; speedup 1.0000x reference)
//
#include <hip/hip_runtime.h>
#include <hip/hip_bf16.h>
#include <math.h>

// ---------------------------------------------------------------------------
// GCN 3-layer forward. R5: (1) packed int2 (col,val) CSR -> one line-write
// per edge; (2) LDS-free register-fragment MFMA GEMMs (no barriers, no bank
// conflicts); (3) 8-way MLP gathers.
// ---------------------------------------------------------------------------

using short8  = __attribute__((ext_vector_type(8))) short;
using floatx4 = __attribute__((ext_vector_type(4))) float;

__device__ inline float bf2f(unsigned int u16) {
    union { unsigned int i; float f; } x; x.i = u16 << 16; return x.f;
}
__device__ inline unsigned short f2bf(float f) {
    union { float f; unsigned int i; } x; x.f = f;
    unsigned int lsb = (x.i >> 16) & 1u;
    return (unsigned short)((x.i + 0x7fffu + lsb) >> 16);
}

// ---------------- CSR build ----------------
__global__ void k_zero_i32(int* p, int n) {
    int i = blockIdx.x * 256 + threadIdx.x;
    if (i < n) p[i] = 0;
}

__global__ void k_deg_count(const int* __restrict__ dst, int* deg, int e) {
    int i = blockIdx.x * 256 + threadIdx.x;
    if (i < e) atomicAdd(&deg[dst[i]], 1);
}

__global__ void k_dis(const int* __restrict__ deg, float* dis, int n) {
    int i = blockIdx.x * 256 + threadIdx.x;
    if (i < n) dis[i] = rsqrtf((float)(deg[i] + 1));   // +1 self loop
}

__global__ void k_scan_block(const int* __restrict__ deg, int* incl, int* bsum, int n) {
    __shared__ int s[256];
    int tid = threadIdx.x;
    int i = blockIdx.x * 256 + tid;
    int v = (i < n) ? deg[i] : 0;
    s[tid] = v;
    __syncthreads();
    for (int off = 1; off < 256; off <<= 1) {
        int t = (tid >= off) ? s[tid - off] : 0;
        __syncthreads();
        s[tid] += t;
        __syncthreads();
    }
    if (i < n) incl[i] = s[tid];
    if (tid == 255) bsum[blockIdx.x] = s[255];
}

__global__ void k_scan_bsum(int* bsum, int nb) {   // single block, nb <= 256
    __shared__ int s[256];
    int tid = threadIdx.x;
    s[tid] = (tid < nb) ? bsum[tid] : 0;
    __syncthreads();
    for (int off = 1; off < 256; off <<= 1) {
        int t = (tid >= off) ? s[tid - off] : 0;
        __syncthreads();
        s[tid] += t;
        __syncthreads();
    }
    if (tid < nb) bsum[tid] = s[tid];
}

__global__ void k_scan_final(const int* __restrict__ deg, const int* __restrict__ incl,
                             const int* __restrict__ bsum, int* row_start, int* cursor,
                             int n, int e) {
    int i = blockIdx.x * 256 + threadIdx.x;
    if (i == 0) row_start[n] = e;
    if (i >= n) return;
    int base = (blockIdx.x > 0) ? bsum[blockIdx.x - 1] : 0;
    int excl = base + incl[i] - deg[i];
    row_start[i] = excl;
    cursor[i] = excl;
}

// packed (col, val) per edge: one 8B store -> one cache line touched
__global__ void k_csr_fill(const int* __restrict__ src, const int* __restrict__ dst,
                           const float* __restrict__ dis, int* cursor,
                           int2* __restrict__ cv, int e) {
    int i = blockIdx.x * 256 + threadIdx.x;
    if (i >= e) return;
    int s = src[i], d = dst[i];
    int pos = atomicAdd(&cursor[d], 1);
    float w = dis[s] * dis[d];
    cv[pos] = make_int2(s, __float_as_int(w));
}

// ---------------- W transpose + bf16 cast: Wt[f][k] = bf16(W[k][f]) --------
__global__ void k_wt(const float* __restrict__ W, unsigned short* __restrict__ Wt,
                     int K, int F) {
    int i = blockIdx.x * 256 + threadIdx.x;
    if (i >= K * F) return;
    int k = i / F, f = i % F;
    Wt[(size_t)f * K + k] = f2bf(W[i]);
}

// ---------------- LDS-free register-fragment MFMA GEMM --------------------
// C[n x BN](bf16) = A[n x K] @ Wt^T.  Block = 256 thr = 4 waves; each wave
// owns 32 rows (two 16-row groups) x BN cols. A fragments loaded directly
// global->reg; B fragments from L2-resident Wt. No LDS, no barriers.
template <int K, int BN, bool A_BF16>
__global__ __launch_bounds__(256) void k_gemm_reg(const void* __restrict__ Av,
                                                  const unsigned short* __restrict__ Wt,
                                                  unsigned short* __restrict__ C, int n) {
    constexpr int NT = BN / 16;
    const int tid = threadIdx.x;
    const int wv = tid >> 6;
    const int lane = tid & 63;
    const int m = lane & 15;
    const int quad = lane >> 4;
    const int rowb = blockIdx.x * 128 + wv * 32;
    const int r0 = min(rowb + m, n - 1);        // clamped loads; stores guarded
    const int r1 = min(rowb + 16 + m, n - 1);

    floatx4 acc0[NT] = {};
    floatx4 acc1[NT] = {};

    for (int k0 = 0; k0 < K; k0 += 32) {
        short8 a0, a1;
        if constexpr (A_BF16) {
            const unsigned short* A = (const unsigned short*)Av;
            a0 = *(const short8*)&A[(size_t)r0 * K + k0 + quad * 8];
            a1 = *(const short8*)&A[(size_t)r1 * K + k0 + quad * 8];
        } else {
            const float* A = (const float*)Av;
            float4 f0 = *(const float4*)&A[(size_t)r0 * K + k0 + quad * 8];
            float4 f1 = *(const float4*)&A[(size_t)r0 * K + k0 + quad * 8 + 4];
            float4 g0 = *(const float4*)&A[(size_t)r1 * K + k0 + quad * 8];
            float4 g1 = *(const float4*)&A[(size_t)r1 * K + k0 + quad * 8 + 4];
            a0[0] = (short)f2bf(f0.x); a0[1] = (short)f2bf(f0.y);
            a0[2] = (short)f2bf(f0.z); a0[3] = (short)f2bf(f0.w);
            a0[4] = (short)f2bf(f1.x); a0[5] = (short)f2bf(f1.y);
            a0[6] = (short)f2bf(f1.z); a0[7] = (short)f2bf(f1.w);
            a1[0] = (short)f2bf(g0.x); a1[1] = (short)f2bf(g0.y);
            a1[2] = (short)f2bf(g0.z); a1[3] = (short)f2bf(g0.w);
            a1[4] = (short)f2bf(g1.x); a1[5] = (short)f2bf(g1.y);
            a1[6] = (short)f2bf(g1.z); a1[7] = (short)f2bf(g1.w);
        }
#pragma unroll
        for (int t = 0; t < NT; ++t) {
            short8 b = *(const short8*)&Wt[(size_t)(t * 16 + m) * K + k0 + quad * 8];
            acc0[t] = __builtin_amdgcn_mfma_f32_16x16x32_bf16(a0, b, acc0[t], 0, 0, 0);
            acc1[t] = __builtin_amdgcn_mfma_f32_16x16x32_bf16(a1, b, acc1[t], 0, 0, 0);
        }
    }

    // C/D layout: col = lane&15, row = quad*4 + reg
#pragma unroll
    for (int t = 0; t < NT; ++t) {
        int cc = t * 16 + m;
#pragma unroll
        for (int r = 0; r < 4; ++r) {
            int ga = rowb + quad * 4 + r;
            if (ga < n) C[(size_t)ga * BN + cc] = f2bf(acc0[t][r]);
            int gb = rowb + 16 + quad * 4 + r;
            if (gb < n) C[(size_t)gb * BN + cc] = f2bf(acc1[t][r]);
        }
    }
}

// ---------------- Gather F=128 (bf16 h/out), fused bias(+relu) -------------
// 8-way MLP: 8 independent h-row loads per round (clamped idx, zeroed weight).
template <bool RELU>
__global__ __launch_bounds__(256) void k_gather128(
        const int* __restrict__ rs, const int2* __restrict__ cv,
        const float* __restrict__ dis,
        const unsigned short* __restrict__ h, const float* __restrict__ bias,
        unsigned short* __restrict__ out, int n) {
    int node = (blockIdx.x * 256 + threadIdx.x) >> 6;
    int lane = threadIdx.x & 63;
    if (node >= n) return;
    int c = lane * 2;
    float di = dis[node];
    unsigned int hv = *(const unsigned int*)&h[(size_t)node * 128 + c];
    float ax0 = bf2f(hv & 0xffffu) * di * di;
    float ay0 = bf2f(hv >> 16) * di * di;
    float ax1 = 0.f, ay1 = 0.f, ax2 = 0.f, ay2 = 0.f, ax3 = 0.f, ay3 = 0.f;
    int beg = rs[node], end = rs[node + 1];
    int last = end - 1;
    for (int j = beg; j < end; j += 8) {
        int2 c0 = cv[j];
        int2 c1 = cv[min(j + 1, last)];
        int2 c2 = cv[min(j + 2, last)];
        int2 c3 = cv[min(j + 3, last)];
        int2 c4 = cv[min(j + 4, last)];
        int2 c5 = cv[min(j + 5, last)];
        int2 c6 = cv[min(j + 6, last)];
        int2 c7 = cv[min(j + 7, last)];
        float w0 = __int_as_float(c0.y);
        float w1 = (j + 1 < end) ? __int_as_float(c1.y) : 0.f;
        float w2 = (j + 2 < end) ? __int_as_float(c2.y) : 0.f;
        float w3 = (j + 3 < end) ? __int_as_float(c3.y) : 0.f;
        float w4 = (j + 4 < end) ? __int_as_float(c4.y) : 0.f;
        float w5 = (j + 5 < end) ? __int_as_float(c5.y) : 0.f;
        float w6 = (j + 6 < end) ? __int_as_float(c6.y) : 0.f;
        float w7 = (j + 7 < end) ? __int_as_float(c7.y) : 0.f;
        unsigned int v0 = *(const unsigned int*)&h[(size_t)c0.x * 128 + c];
        unsigned int v1 = *(const unsigned int*)&h[(size_t)c1.x * 128 + c];
        unsigned int v2 = *(const unsigned int*)&h[(size_t)c2.x * 128 + c];
        unsigned int v3 = *(const unsigned int*)&h[(size_t)c3.x * 128 + c];
        unsigned int v4 = *(const unsigned int*)&h[(size_t)c4.x * 128 + c];
        unsigned int v5 = *(const unsigned int*)&h[(size_t)c5.x * 128 + c];
        unsigned int v6 = *(const unsigned int*)&h[(size_t)c6.x * 128 + c];
        unsigned int v7 = *(const unsigned int*)&h[(size_t)c7.x * 128 + c];
        ax0 += w0 * bf2f(v0 & 0xffffu) + w1 * bf2f(v1 & 0xffffu);
        ay0 += w0 * bf2f(v0 >> 16)     + w1 * bf2f(v1 >> 16);
        ax1 += w2 * bf2f(v2 & 0xffffu) + w3 * bf2f(v3 & 0xffffu);
        ay1 += w2 * bf2f(v2 >> 16)     + w3 * bf2f(v3 >> 16);
        ax2 += w4 * bf2f(v4 & 0xffffu) + w5 * bf2f(v5 & 0xffffu);
        ay2 += w4 * bf2f(v4 >> 16)     + w5 * bf2f(v5 >> 16);
        ax3 += w6 * bf2f(v6 & 0xffffu) + w7 * bf2f(v7 & 0xffffu);
        ay3 += w6 * bf2f(v6 >> 16)     + w7 * bf2f(v7 >> 16);
    }
    float ax = (ax0 + ax1) + (ax2 + ax3) + bias[c];
    float ay = (ay0 + ay1) + (ay2 + ay3) + bias[c + 1];
    if (RELU) { ax = fmaxf(ax, 0.f); ay = fmaxf(ay, 0.f); }
    unsigned int o = (unsigned int)f2bf(ax) | ((unsigned int)f2bf(ay) << 16);
    *(unsigned int*)&out[(size_t)node * 128 + c] = o;
}

// ---------------- Gather F=64 (bf16 h) + bias + log_softmax (fp32 out) -----
__global__ __launch_bounds__(256) void k_gather64_lsm(
        const int* __restrict__ rs, const int2* __restrict__ cv,
        const float* __restrict__ dis,
        const unsigned short* __restrict__ h, const float* __restrict__ bias,
        float* __restrict__ out, int n) {
    int node = (blockIdx.x * 256 + threadIdx.x) >> 6;
    int lane = threadIdx.x & 63;
    if (node >= n) return;
    float di = dis[node];
    float a0 = bf2f(h[(size_t)node * 64 + lane]) * di * di;
    float a1 = 0.f, a2 = 0.f, a3 = 0.f;
    int beg = rs[node], end = rs[node + 1];
    int last = end - 1;
    for (int j = beg; j < end; j += 8) {
        int2 c0 = cv[j];
        int2 c1 = cv[min(j + 1, last)];
        int2 c2 = cv[min(j + 2, last)];
        int2 c3 = cv[min(j + 3, last)];
        int2 c4 = cv[min(j + 4, last)];
        int2 c5 = cv[min(j + 5, last)];
        int2 c6 = cv[min(j + 6, last)];
        int2 c7 = cv[min(j + 7, last)];
        float w0 = __int_as_float(c0.y);
        float w1 = (j + 1 < end) ? __int_as_float(c1.y) : 0.f;
        float w2 = (j + 2 < end) ? __int_as_float(c2.y) : 0.f;
        float w3 = (j + 3 < end) ? __int_as_float(c3.y) : 0.f;
        float w4 = (j + 4 < end) ? __int_as_float(c4.y) : 0.f;
        float w5 = (j + 5 < end) ? __int_as_float(c5.y) : 0.f;
        float w6 = (j + 6 < end) ? __int_as_float(c6.y) : 0.f;
        float w7 = (j + 7 < end) ? __int_as_float(c7.y) : 0.f;
        float h0 = bf2f(h[(size_t)c0.x * 64 + lane]);
        float h1 = bf2f(h[(size_t)c1.x * 64 + lane]);
        float h2 = bf2f(h[(size_t)c2.x * 64 + lane]);
        float h3 = bf2f(h[(size_t)c3.x * 64 + lane]);
        float h4 = bf2f(h[(size_t)c4.x * 64 + lane]);
        float h5 = bf2f(h[(size_t)c5.x * 64 + lane]);
        float h6 = bf2f(h[(size_t)c6.x * 64 + lane]);
        float h7 = bf2f(h[(size_t)c7.x * 64 + lane]);
        a0 += w0 * h0 + w1 * h1;
        a1 += w2 * h2 + w3 * h3;
        a2 += w4 * h4 + w5 * h5;
        a3 += w6 * h6 + w7 * h7;
    }
    float v = (a0 + a1) + (a2 + a3) + bias[lane];
    float mm = v;
#pragma unroll
    for (int s = 32; s; s >>= 1) mm = fmaxf(mm, __shfl_xor(mm, s));
    float e = expf(v - mm);
    float sum = e;
#pragma unroll
    for (int s = 32; s; s >>= 1) sum += __shfl_xor(sum, s);
    out[(size_t)node * 64 + lane] = (v - mm) - logf(sum);
}

extern "C" void kernel_launch(void* const* d_in, const int* in_sizes, int n_in,
                              void* d_out, int out_size, void* d_ws, size_t ws_size,
                              hipStream_t stream) {
    constexpr int IN = 512, HID = 128, OUT = 64;
    const float* feats = (const float*)d_in[0];
    const int*   adj   = (const int*)d_in[1];
    const float* W1 = (const float*)d_in[2];
    const float* b1 = (const float*)d_in[3];
    const float* W2 = (const float*)d_in[4];
    const float* b2 = (const float*)d_in[5];
    const float* W3 = (const float*)d_in[6];
    const float* b3 = (const float*)d_in[7];
    float* out = (float*)d_out;

    const int n = in_sizes[0] / IN;      // 50000
    const int e = in_sizes[1] / 2;       // 800000
    const int* srcp = adj;
    const int* dstp = adj + e;

    // workspace layout
    char* ws = (char*)d_ws;
    int*   deg  = (int*)ws;                    ws += (size_t)n * 4;
    float* dis  = (float*)ws;                  ws += (size_t)n * 4;
    int*   incl = (int*)ws;                    ws += (size_t)n * 4;
    int*   bsum = (int*)ws;                    ws += 256 * 4;
    int*   rs   = (int*)ws;                    ws += (size_t)(n + 1) * 4 + 4;
    int*   curs = (int*)ws;                    ws += (size_t)n * 4;
    int2*  cv   = (int2*)ws;                   ws += (size_t)e * 8;
    unsigned short* Wt1 = (unsigned short*)ws; ws += (size_t)IN * HID * 2;
    unsigned short* Wt2 = (unsigned short*)ws; ws += (size_t)HID * HID * 2;
    unsigned short* Wt3 = (unsigned short*)ws; ws += (size_t)HID * OUT * 2;
    unsigned short* hb  = (unsigned short*)ws; ws += (size_t)n * HID * 2;
    unsigned short* xb  = (unsigned short*)ws; ws += (size_t)n * HID * 2;

    const int nb_n = (n + 255) / 256;
    const int nb_e = (e + 255) / 256;
    const int nb_g = (n + 127) / 128;        // reg-GEMM blocks (128 rows/block)
    const int nb_w = (n * 64 + 255) / 256;   // 1 wave/node kernels

    // ---- build CSR (by dst) + symmetric norm
    k_zero_i32<<<nb_n, 256, 0, stream>>>(deg, n);
    k_deg_count<<<nb_e, 256, 0, stream>>>(dstp, deg, e);
    k_dis<<<nb_n, 256, 0, stream>>>(deg, dis, n);
    k_scan_block<<<nb_n, 256, 0, stream>>>(deg, incl, bsum, n);
    k_scan_bsum<<<1, 256, 0, stream>>>(bsum, nb_n);
    k_scan_final<<<nb_n, 256, 0, stream>>>(deg, incl, bsum, rs, curs, n, e);
    k_csr_fill<<<nb_e, 256, 0, stream>>>(srcp, dstp, dis, curs, cv, e);

    // ---- weight transposes (fp32 -> bf16, [K][F] -> [F][K])
    k_wt<<<(IN * HID + 255) / 256, 256, 0, stream>>>(W1, Wt1, IN, HID);
    k_wt<<<(HID * HID + 255) / 256, 256, 0, stream>>>(W2, Wt2, HID, HID);
    k_wt<<<(HID * OUT + 255) / 256, 256, 0, stream>>>(W3, Wt3, HID, OUT);

    // ---- layer 1: 512 -> 128, gather + bias + relu
    k_gemm_reg<IN, HID, false><<<nb_g, 256, 0, stream>>>(feats, Wt1, hb, n);
    k_gather128<true><<<nb_w, 256, 0, stream>>>(rs, cv, dis, hb, b1, xb, n);

    // ---- layer 2: 128 -> 128, gather + bias + relu
    k_gemm_reg<HID, HID, true><<<nb_g, 256, 0, stream>>>(xb, Wt2, hb, n);
    k_gather128<true><<<nb_w, 256, 0, stream>>>(rs, cv, dis, hb, b2, xb, n);

    // ---- layer 3: 128 -> 64, gather + bias + log_softmax
    k_gemm_reg<HID, OUT, true><<<nb_g, 256, 0, stream>>>(xb, Wt3, hb, n);
    k_gather64_lsm<<<nb_w, 256, 0, stream>>>(rs, cv, dis, hb, b3, out, n);
}